// Round 1
// baseline (12509.493 us; speedup 1.0000x reference)
//
#include <hip/hip_runtime.h>
#include <hip/hip_bf16.h>
#include <math.h>

#define Bsz 4
#define Sseq 1024
#define Dm 1024
#define Hh 16
#define DHd 64
#define Ll 4
#define Vv 32000
#define NT (Bsz*Sseq)   /* 4096 tokens */
#define Dff 4096

// ---------------- state encoder + positional embeddings ----------------
// one block per token; tiny MLP 4->16->16->D with tanh, then add pos embs
__global__ __launch_bounds__(256) void encoder_kernel(
    const float* __restrict__ states, const int* __restrict__ timesteps,
    const float* __restrict__ w1, const float* __restrict__ b1,
    const float* __restrict__ w2, const float* __restrict__ b2,
    const float* __restrict__ w3, const float* __restrict__ b3,
    const float* __restrict__ pos_emb, const float* __restrict__ gpe,
    float* __restrict__ x)
{
  int bs = blockIdx.x;
  int b = bs / Sseq, s = bs % Sseq;
  int tid = threadIdx.x;
  __shared__ float st[4], h1[16], h2[16];
  if (tid < 4) st[tid] = states[bs*4 + tid];
  __syncthreads();
  if (tid < 16) {
    float a = b1[tid];
    #pragma unroll
    for (int j=0;j<4;++j) a += st[j]*w1[j*16+tid];
    h1[tid] = fmaxf(a, 0.f);
  }
  __syncthreads();
  if (tid < 16) {
    float a = b2[tid];
    #pragma unroll
    for (int j=0;j<16;++j) a += h1[j]*w2[j*16+tid];
    h2[tid] = fmaxf(a, 0.f);
  }
  __syncthreads();
  int t = timesteps[b];
  const float* gr = gpe + (size_t)t*Dm;
  const float* pr = pos_emb + (size_t)s*Dm;
  float* xr = x + (size_t)bs*Dm;
  for (int o = tid; o < Dm; o += 256) {
    float a = b3[o];
    #pragma unroll
    for (int j=0;j<16;++j) a += h2[j]*w3[j*Dm+o];
    xr[o] = tanhf(a) + gr[o] + pr[o];
  }
}

// ---------------- layernorm, one block per token (row of 1024) ----------------
__global__ __launch_bounds__(256) void ln_kernel(
    const float* __restrict__ in, const float* __restrict__ g,
    const float* __restrict__ bb, float* __restrict__ out)
{
  int row = blockIdx.x, tid = threadIdx.x;
  const float* xr = in + (size_t)row*Dm;
  float vals[4];
  float s = 0.f;
  #pragma unroll
  for (int i=0;i<4;++i) { vals[i] = xr[tid + i*256]; s += vals[i]; }
  __shared__ float red[8];
  float v = s;
  #pragma unroll
  for (int off=32; off>0; off>>=1) v += __shfl_down(v, off, 64);
  if ((tid & 63) == 0) red[tid>>6] = v;
  __syncthreads();
  float mu = (red[0]+red[1]+red[2]+red[3]) * (1.f/Dm);
  float vs = 0.f;
  #pragma unroll
  for (int i=0;i<4;++i) { float d = vals[i]-mu; vs += d*d; }
  v = vs;
  #pragma unroll
  for (int off=32; off>0; off>>=1) v += __shfl_down(v, off, 64);
  if ((tid & 63) == 0) red[4+(tid>>6)] = v;
  __syncthreads();
  float var = (red[4]+red[5]+red[6]+red[7]) * (1.f/Dm);
  float inv = rsqrtf(var + 1e-5f);
  float* orow = out + (size_t)row*Dm;
  #pragma unroll
  for (int i=0;i<4;++i) {
    int c = tid + i*256;
    orow[c] = (vals[i]-mu)*inv*g[c] + bb[c];
  }
}

// ---------------- generic tiled fp32 GEMM: C = epi(A[M,K] @ W[K,N]) ----------------
// EPI: 0 = none, 2 = +bias +resid, 3 = +bias then exact GELU, 1 = +bias
template<int EPI>
__global__ __launch_bounds__(256) void gemm_kernel(
    const float* __restrict__ A, const float* __restrict__ W,
    const float* __restrict__ bias, const float* __restrict__ resid,
    float* __restrict__ C, int M, int N, int K)
{
  __shared__ float As[16][64];
  __shared__ float Ws[16][64];
  int tid = threadIdx.x;
  int n0 = blockIdx.x*64, m0 = blockIdx.y*64;
  int tm = (tid>>4)<<2, tn = (tid&15)<<2;
  int la_r = tid>>2, la_k = (tid&3)<<2;   // A-tile load: row 0..63, k-chunk of 4
  int lw_k = tid>>4, lw_n = (tid&15)<<2;  // W-tile load: k-row 0..15, 4 cols
  float acc[4][4] = {};
  const float* Aptr = A + (size_t)(m0+la_r)*K + la_k;
  const float* Wptr = W + (size_t)lw_k*N + n0 + lw_n;
  for (int k0=0; k0<K; k0+=16) {
    float4 av = *(const float4*)(Aptr + k0);
    float4 wv = *(const float4*)(Wptr + (size_t)k0*N);
    __syncthreads();
    As[la_k+0][la_r]=av.x; As[la_k+1][la_r]=av.y; As[la_k+2][la_r]=av.z; As[la_k+3][la_r]=av.w;
    *(float4*)&Ws[lw_k][lw_n] = wv;
    __syncthreads();
    #pragma unroll
    for (int kk=0; kk<16; ++kk) {
      float4 a4 = *(const float4*)&As[kk][tm];
      float4 w4 = *(const float4*)&Ws[kk][tn];
      float ar[4] = {a4.x,a4.y,a4.z,a4.w};
      float wr[4] = {w4.x,w4.y,w4.z,w4.w};
      #pragma unroll
      for (int i=0;i<4;++i)
        #pragma unroll
        for (int j=0;j<4;++j)
          acc[i][j] = fmaf(ar[i], wr[j], acc[i][j]);
    }
  }
  #pragma unroll
  for (int i=0;i<4;++i) {
    int m = m0+tm+i;
    #pragma unroll
    for (int j=0;j<4;++j) {
      int n = n0+tn+j;
      float vv = acc[i][j];
      if (EPI >= 1) vv += bias[n];
      if (EPI == 2) vv += resid[(size_t)m*N + n];
      if (EPI == 3) vv = 0.5f*vv*(1.f + erff(vv*0.70710678118654752f));
      C[(size_t)m*N + n] = vv;
    }
  }
}

// ---------------- flash attention, 64x64 tiles, one block per (q-tile, b, h) ----------------
__global__ __launch_bounds__(256) void attn_kernel(
    const float* __restrict__ q, const float* __restrict__ k,
    const float* __restrict__ v, float* __restrict__ y)
{
  int qi = blockIdx.x;        // S/64 q-tiles
  int bh = blockIdx.y;        // B*H
  int b = bh >> 4, h = bh & 15;
  int tid = threadIdx.x;
  __shared__ float Qs[64][64], Ks[64][64], Vs[64][64], Ps[64][64];
  __shared__ float pmax[64][4], psum[64][4];
  __shared__ float mrow[64], lrow[64];
  const size_t base = ((size_t)b*Sseq)*Dm + (size_t)h*DHd;
  int s0 = qi*64;
  int lr = tid>>4, lc = (tid&15)<<2;
  #pragma unroll
  for (int it=0; it<4; ++it) {
    int r = lr + it*16;
    *(float4*)&Qs[r][lc] = *(const float4*)&q[base + (size_t)(s0+r)*Dm + lc];
  }
  if (tid < 64) { mrow[tid] = -INFINITY; lrow[tid] = 0.f; }
  int orow = tid>>2, oc0 = (tid&3)<<4;   // this thread: score row orow, t/col chunk of 16
  float O[16];
  #pragma unroll
  for (int c=0;c<16;++c) O[c]=0.f;
  const float scale = 0.125f;  // 1/sqrt(64)
  __syncthreads();
  for (int kj=0; kj<=qi; ++kj) {
    int t0g = kj*64;
    float mold = mrow[orow], lold = lrow[orow];
    #pragma unroll
    for (int it=0; it<4; ++it) {
      int r = lr + it*16;
      *(float4*)&Ks[r][lc] = *(const float4*)&k[base + (size_t)(t0g+r)*Dm + lc];
      *(float4*)&Vs[r][lc] = *(const float4*)&v[base + (size_t)(t0g+r)*Dm + lc];
    }
    __syncthreads();  // (A) K,V visible; mold/lold read done
    float sc[16];
    #pragma unroll
    for (int j=0;j<16;++j) sc[j]=0.f;
    for (int kk=0; kk<64; kk+=4) {
      float4 qv = *(const float4*)&Qs[orow][kk];
      #pragma unroll
      for (int j=0;j<16;++j) {
        float4 kv = *(const float4*)&Ks[oc0+j][kk];
        sc[j] += qv.x*kv.x + qv.y*kv.y + qv.z*kv.z + qv.w*kv.w;
      }
    }
    float tmax = -INFINITY;
    #pragma unroll
    for (int j=0;j<16;++j) {
      float val = sc[j]*scale;
      if (kj==qi && (t0g+oc0+j) > (s0+orow)) val = -INFINITY;
      sc[j]=val;
      tmax = fmaxf(tmax, val);
    }
    pmax[orow][tid&3] = tmax;
    __syncthreads();  // (B)
    float mnew = fmaxf(mold, fmaxf(fmaxf(pmax[orow][0],pmax[orow][1]),
                                   fmaxf(pmax[orow][2],pmax[orow][3])));
    float alpha = expf(mold - mnew);   // mold=-inf on first tile -> 0
    float lsum = 0.f;
    #pragma unroll
    for (int j=0;j<16;++j) {
      float p = expf(sc[j]-mnew);      // masked -inf -> 0
      Ps[orow][oc0+j] = p;
      lsum += p;
    }
    psum[orow][tid&3] = lsum;
    __syncthreads();  // (C1) P and partial sums visible
    float lnew = lold*alpha + psum[orow][0]+psum[orow][1]+psum[orow][2]+psum[orow][3];
    if ((tid&3)==0) { mrow[orow]=mnew; lrow[orow]=lnew; }
    #pragma unroll
    for (int c=0;c<16;++c) O[c] *= alpha;
    for (int t=0;t<64;++t) {
      float p = Ps[orow][t];
      #pragma unroll
      for (int c=0;c<16;c+=4) {
        float4 vv = *(const float4*)&Vs[t][oc0+c];
        O[c+0] = fmaf(p, vv.x, O[c+0]);
        O[c+1] = fmaf(p, vv.y, O[c+1]);
        O[c+2] = fmaf(p, vv.z, O[c+2]);
        O[c+3] = fmaf(p, vv.w, O[c+3]);
      }
    }
    __syncthreads(); // (C2) protect Ks/Vs/Ps/stats for next tile
  }
  float linv = 1.f / lrow[orow];
  #pragma unroll
  for (int c=0;c<16;++c) {
    y[base + (size_t)(s0+orow)*Dm + oc0 + c] = O[c]*linv;
  }
}

extern "C" void kernel_launch(void* const* d_in, const int* in_sizes, int n_in,
                              void* d_out, int out_size, void* d_ws, size_t ws_size,
                              hipStream_t stream)
{
  const float* states   = (const float*)d_in[0];
  const int*   timesteps= (const int*)d_in[1];
  const float* se_w1=(const float*)d_in[2];  const float* se_b1=(const float*)d_in[3];
  const float* se_w2=(const float*)d_in[4];  const float* se_b2=(const float*)d_in[5];
  const float* se_w3=(const float*)d_in[6];  const float* se_b3=(const float*)d_in[7];
  const float* pos_emb=(const float*)d_in[8];const float* gpe=(const float*)d_in[9];
  const float* ln1_g=(const float*)d_in[10]; const float* ln1_b=(const float*)d_in[11];
  const float* Wq=(const float*)d_in[12];    const float* Wk=(const float*)d_in[13];
  const float* Wv=(const float*)d_in[14];    const float* Wp=(const float*)d_in[15];
  const float* bp=(const float*)d_in[16];
  const float* ln2_g=(const float*)d_in[17]; const float* ln2_b=(const float*)d_in[18];
  const float* W1=(const float*)d_in[19];    const float* b1=(const float*)d_in[20];
  const float* W2=(const float*)d_in[21];    const float* b2=(const float*)d_in[22];
  const float* lnf_g=(const float*)d_in[23]; const float* lnf_b=(const float*)d_in[24];
  const float* head_w=(const float*)d_in[25];
  float* out = (float*)d_out;

  const size_t TD = (size_t)NT*Dm; // 4M floats per activation buffer
  float* x  = (float*)d_ws;  // 16 MB each
  float* hn = x + TD;
  float* q  = hn + TD;
  float* k  = q + TD;
  float* v  = k + TD;
  float* y  = v + TD;
  float* hmlp = q;           // alias: q..y region = 4*TD = NT*Dff floats exactly

  encoder_kernel<<<NT, 256, 0, stream>>>(states, timesteps, se_w1, se_b1, se_w2,
                                         se_b2, se_w3, se_b3, pos_emb, gpe, x);

  dim3 gDD(Dm/64, NT/64);
  for (int l=0; l<Ll; ++l) {
    const float* wq = Wq + (size_t)l*Dm*Dm;
    const float* wk = Wk + (size_t)l*Dm*Dm;
    const float* wv = Wv + (size_t)l*Dm*Dm;
    const float* wp = Wp + (size_t)l*Dm*Dm;
    const float* w1 = W1 + (size_t)l*Dm*Dff;
    const float* w2 = W2 + (size_t)l*Dff*Dm;

    ln_kernel<<<NT,256,0,stream>>>(x, ln1_g + l*Dm, ln1_b + l*Dm, hn);
    gemm_kernel<0><<<gDD,256,0,stream>>>(hn, wq, nullptr, nullptr, q, NT, Dm, Dm);
    gemm_kernel<0><<<gDD,256,0,stream>>>(hn, wk, nullptr, nullptr, k, NT, Dm, Dm);
    gemm_kernel<0><<<gDD,256,0,stream>>>(hn, wv, nullptr, nullptr, v, NT, Dm, Dm);
    attn_kernel<<<dim3(Sseq/64, Bsz*Hh),256,0,stream>>>(q, k, v, y);
    gemm_kernel<2><<<gDD,256,0,stream>>>(y, wp, bp + l*Dm, x, x, NT, Dm, Dm);
    ln_kernel<<<NT,256,0,stream>>>(x, ln2_g + l*Dm, ln2_b + l*Dm, hn);
    gemm_kernel<3><<<dim3(Dff/64, NT/64),256,0,stream>>>(hn, w1, b1 + l*Dff, nullptr,
                                                         hmlp, NT, Dff, Dm);
    gemm_kernel<2><<<gDD,256,0,stream>>>(hmlp, w2, b2 + l*Dm, x, x, NT, Dm, Dff);
  }
  ln_kernel<<<NT,256,0,stream>>>(x, lnf_g, lnf_b, hn);
  gemm_kernel<0><<<dim3(Vv/64, NT/64),256,0,stream>>>(hn, head_w, nullptr, nullptr,
                                                      out, NT, Vv, Dm);
}